// Round 1
// baseline (304.262 us; speedup 1.0000x reference)
//
#include <hip/hip_runtime.h>
#include <hip/hip_bf16.h>
#include <math.h>

#define D 256
#define HID 16

typedef __attribute__((ext_vector_type(8))) short bf16x8;
typedef __attribute__((ext_vector_type(4))) float f32x4;

__device__ __forceinline__ ushort f2b(float x){
  uint u = __float_as_uint(x);
  u = u + 0x7FFFu + ((u >> 16) & 1u);   // round-to-nearest-even
  return (ushort)(u >> 16);
}
__device__ __forceinline__ float b2f(ushort u){ return __uint_as_float(((uint)u) << 16); }

// ---- 64-entry attention table: att[vr*8+vc] = sigmoid(relu([vr,vc]@Wa1+ba1)@Wa2+ba2)
__global__ void att_table_kernel(const float* Wa1, const float* ba1,
                                 const float* Wa2, const float* ba2, float* tab){
  int t = threadIdx.x;
  if (t >= 64) return;
  float vr = (float)(t >> 3), vc = (float)(t & 7);
  float s = ba2[0];
  #pragma unroll
  for (int j = 0; j < HID; ++j){
    float hj = fmaxf(vr * Wa1[j] + vc * Wa1[HID + j] + ba1[j], 0.f);
    s += hj * Wa2[j];
  }
  tab[t] = 1.f / (1.f + expf(-s));
}

// ---- f32 -> bf16 convert
__global__ void conv_kernel(const float* in, ushort* out, int n){
  int i = blockIdx.x * blockDim.x + threadIdx.x;
  if (i < n) out[i] = f2b(in[i]);
}

// ---- pack weight W[256,256] (row-major, k-major) into MFMA B-fragment layout:
// out[((kt*16+nt)*64+lane)*8+i] = W[kt*32 + (lane>>4)*8 + i][nt*16 + (lane&15)]
__global__ void pack_b_kernel(const float* W, ushort* out){
  int p = blockIdx.x * blockDim.x + threadIdx.x; // 0..65535
  int i = p & 7, l = (p >> 3) & 63, nt = (p >> 9) & 15, kt = p >> 13;
  int k = kt * 32 + ((l >> 4) * 8) + i;
  int n = nt * 16 + (l & 15);
  out[p] = f2b(W[k * 256 + n]);
}

// ---- edge bucketing (counting sort by row) ----
__global__ void count_kernel(const int* row, int* deg, int E){
  int e = blockIdx.x * blockDim.x + threadIdx.x;
  if (e < E) atomicAdd(&deg[row[e]], 1);
}

__global__ void scan_kernel(const int* deg, int* off, int* cur, int N){
  const int CH = 16; // 1024*16 = 16384 >= N
  int t = threadIdx.x;
  int vals[CH], loc[CH]; int s = 0;
  #pragma unroll
  for (int i = 0; i < CH; ++i){
    int idx = t * CH + i;
    int v = (idx < N) ? deg[idx] : 0;
    vals[i] = v; loc[i] = s; s += v;
  }
  __shared__ int sm[1024];
  sm[t] = s;
  __syncthreads();
  for (int d = 1; d < 1024; d <<= 1){
    int v = (t >= d) ? sm[t - d] : 0;
    __syncthreads();
    sm[t] += v;
    __syncthreads();
  }
  int excl = sm[t] - s;
  #pragma unroll
  for (int i = 0; i < CH; ++i){
    int idx = t * CH + i;
    if (idx < N){
      int o = excl + loc[i];
      off[idx] = o; cur[idx] = o;
      if (idx == N - 1) off[N] = o + vals[i];
    }
  }
}

__global__ void fill_kernel(const int* ei, const int* val, const float* tab,
                            int* cur, uint2* elist, int E){
  int e = blockIdx.x * blockDim.x + threadIdx.x;
  if (e >= E) return;
  int r = ei[e], c = ei[E + e];
  int vr = val[r], vc = val[c];
  float att = tab[vr * 8 + vc];
  int pos = atomicAdd(&cur[r], 1);
  elist[pos] = make_uint2((uint)c | ((uint)vc << 16), __float_as_uint(att));
}

// ---- phase2: per-row edge aggregation.
// Q[r] = sum_e att * relu(P1[r] + P2[col] + vr*wvr + vc*wvc + bm1); S[r] = sum_e att
__global__ __launch_bounds__(256) void phase2_kernel(
    const float* P1, const ushort* P2, const int* off, const uint2* elist,
    const int* val, const float* Wm1, const float* bm1,
    ushort* Qbf, float* S, int N){
  int wave = threadIdx.x >> 6, lane = threadIdx.x & 63;
  int r = blockIdx.x * 4 + wave;
  if (r >= N) return;
  int f0 = lane * 4;
  const float* wvr = Wm1 + 512 * 256;
  const float* wvc = Wm1 + 513 * 256;
  float4 p1 = *(const float4*)(P1 + (size_t)r * D + f0);
  float4 wr = *(const float4*)(wvr + f0);
  float4 wv = *(const float4*)(wvc + f0);
  float4 bb = *(const float4*)(bm1 + f0);
  float vrf = (float)val[r];
  float bx = p1.x + vrf * wr.x + bb.x;
  float by = p1.y + vrf * wr.y + bb.y;
  float bz = p1.z + vrf * wr.z + bb.z;
  float bw = p1.w + vrf * wr.w + bb.w;
  float ax = 0.f, ay = 0.f, az = 0.f, aw = 0.f, satt = 0.f;
  int e0 = off[r], e1 = off[r + 1];
  for (int e = e0; e < e1; ++e){
    uint2 p = elist[e];
    int c = (int)(p.x & 0xFFFFu);
    float vcf = (float)(p.x >> 16);
    float att = __uint_as_float(p.y);
    ushort4 pv = *(const ushort4*)(P2 + (size_t)c * D + f0);
    float zx = bx + b2f(pv.x) + vcf * wv.x;
    float zy = by + b2f(pv.y) + vcf * wv.y;
    float zz = bz + b2f(pv.z) + vcf * wv.z;
    float zw = bw + b2f(pv.w) + vcf * wv.w;
    ax += att * fmaxf(zx, 0.f);
    ay += att * fmaxf(zy, 0.f);
    az += att * fmaxf(zz, 0.f);
    aw += att * fmaxf(zw, 0.f);
    satt += att;
  }
  ushort4 q; q.x = f2b(ax); q.y = f2b(ay); q.z = f2b(az); q.w = f2b(aw);
  *(ushort4*)(Qbf + (size_t)r * D + f0) = q;
  if (lane == 0) S[r] = satt;
}

// ---- fused GEMM: C = [relu]( A1@B1 (+ A2@B2) (+ bias) (+ rowscale*rsvec) ) (+ resid)
// A: [M,256] bf16 row-major. B: pre-packed MFMA fragments. Block = 4 waves, 64 rows, full 256 cols.
__global__ __launch_bounds__(256) void gemm_kernel(
    const ushort* A1, const ushort* B1,
    const ushort* A2, const ushort* B2,
    const float* bias, const float* rowscale, const float* rsvec,
    const float* resid, int do_relu,
    float* outF, ushort* outB, int M){
  int wave = threadIdx.x >> 6, lane = threadIdx.x & 63;
  int rbase = blockIdx.x * 64 + wave * 16;
  int arow = min(rbase + (lane & 15), M - 1);
  int klane = (lane >> 4) * 8;
  f32x4 zero = {0.f, 0.f, 0.f, 0.f};
  f32x4 acc[16];
  #pragma unroll
  for (int i = 0; i < 16; ++i) acc[i] = zero;

  {
    const bf16x8* Av = (const bf16x8*)(A1 + (size_t)arow * 256 + klane);
    const bf16x8* Bv = (const bf16x8*)B1;
    #pragma unroll
    for (int kt = 0; kt < 8; ++kt){
      bf16x8 a = Av[kt * 4];
      #pragma unroll
      for (int nt = 0; nt < 16; ++nt){
        bf16x8 b = Bv[(kt * 16 + nt) * 64 + lane];
        acc[nt] = __builtin_amdgcn_mfma_f32_16x16x32_bf16(a, b, acc[nt], 0, 0, 0);
      }
    }
  }
  if (A2){
    const bf16x8* Av = (const bf16x8*)(A2 + (size_t)arow * 256 + klane);
    const bf16x8* Bv = (const bf16x8*)B2;
    #pragma unroll
    for (int kt = 0; kt < 8; ++kt){
      bf16x8 a = Av[kt * 4];
      #pragma unroll
      for (int nt = 0; nt < 16; ++nt){
        bf16x8 b = Bv[(kt * 16 + nt) * 64 + lane];
        acc[nt] = __builtin_amdgcn_mfma_f32_16x16x32_bf16(a, b, acc[nt], 0, 0, 0);
      }
    }
  }

  int col0 = lane & 15, rl0 = (lane >> 4) * 4;
  #pragma unroll
  for (int nt = 0; nt < 16; ++nt){
    int c = nt * 16 + col0;
    float bc = bias ? bias[c] : 0.f;
    float vc2 = rsvec ? rsvec[c] : 0.f;
    #pragma unroll
    for (int j = 0; j < 4; ++j){
      int r = rbase + rl0 + j;
      if (r < M){
        float v = acc[nt][j] + bc;
        if (rowscale) v += rowscale[r] * vc2;
        if (do_relu) v = fmaxf(v, 0.f);
        if (resid) v += resid[(size_t)r * 256 + c];
        if (outF) outF[(size_t)r * 256 + c] = v;
        if (outB) outB[(size_t)r * 256 + c] = f2b(v);
      }
    }
  }
}

extern "C" void kernel_launch(void* const* d_in, const int* in_sizes, int n_in,
                              void* d_out, int out_size, void* d_ws, size_t ws_size,
                              hipStream_t stream){
  const float* h   = (const float*)d_in[0];
  const int*   ei  = (const int*)d_in[1];
  const int*   val = (const int*)d_in[3];
  const float* Wm1 = (const float*)d_in[4];
  const float* bm1 = (const float*)d_in[5];
  const float* Wm2 = (const float*)d_in[6];
  const float* bm2 = (const float*)d_in[7];
  const float* Wu1 = (const float*)d_in[8];
  const float* bu1 = (const float*)d_in[9];
  const float* Wu2 = (const float*)d_in[10];
  const float* bu2 = (const float*)d_in[11];
  const float* Wa1 = (const float*)d_in[12];
  const float* ba1 = (const float*)d_in[13];
  const float* Wa2 = (const float*)d_in[14];
  const float* ba2 = (const float*)d_in[15];
  int N = in_sizes[0] / D;
  int E = in_sizes[1] / 2;
  float* out = (float*)d_out;

  char* ws = (char*)d_ws;
  size_t o = 0;
  auto alloc = [&](size_t bytes)->char*{
    char* p = ws + o; o += (bytes + 255) & ~(size_t)255; return p;
  };
  float*  P1     = (float*) alloc((size_t)N * D * 4);
  ushort* P2     = (ushort*)alloc((size_t)N * D * 2);
  ushort* Hbf    = (ushort*)alloc((size_t)N * D * 2);
  ushort* Qbf    = (ushort*)alloc((size_t)N * D * 2);
  ushort* Haggbf = (ushort*)alloc((size_t)N * D * 2);
  ushort* Tbf    = (ushort*)alloc((size_t)N * D * 2);
  float*  S      = (float*) alloc((size_t)N * 4);
  float*  tab    = (float*) alloc(64 * 4);
  int*    deg    = (int*)   alloc((size_t)N * 4);
  int*    off    = (int*)   alloc(((size_t)N + 1) * 4);
  int*    cur    = (int*)   alloc((size_t)N * 4);
  uint2*  elist  = (uint2*) alloc((size_t)E * 8);
  ushort* pWm1a  = (ushort*)alloc(65536 * 2);
  ushort* pWm1b  = (ushort*)alloc(65536 * 2);
  ushort* pWm2   = (ushort*)alloc(65536 * 2);
  ushort* pWu1a  = (ushort*)alloc(65536 * 2);
  ushort* pWu1b  = (ushort*)alloc(65536 * 2);
  ushort* pWu2   = (ushort*)alloc(65536 * 2);

  hipMemsetAsync(deg, 0, (size_t)N * 4, stream);

  att_table_kernel<<<1, 64, 0, stream>>>(Wa1, ba1, Wa2, ba2, tab);
  conv_kernel<<<(N * D + 255) / 256, 256, 0, stream>>>(h, Hbf, N * D);

  pack_b_kernel<<<256, 256, 0, stream>>>(Wm1,           pWm1a);
  pack_b_kernel<<<256, 256, 0, stream>>>(Wm1 + 65536,   pWm1b);
  pack_b_kernel<<<256, 256, 0, stream>>>(Wm2,           pWm2);
  pack_b_kernel<<<256, 256, 0, stream>>>(Wu1,           pWu1a);
  pack_b_kernel<<<256, 256, 0, stream>>>(Wu1 + 65536,   pWu1b);
  pack_b_kernel<<<256, 256, 0, stream>>>(Wu2,           pWu2);

  count_kernel<<<(E + 255) / 256, 256, 0, stream>>>(ei, deg, E);
  scan_kernel<<<1, 1024, 0, stream>>>(deg, off, cur, N);
  fill_kernel<<<(E + 255) / 256, 256, 0, stream>>>(ei, val, tab, cur, elist, E);

  int gblocks = (N + 63) / 64;
  // P1 = H @ Wm1a  (f32 out)
  gemm_kernel<<<gblocks, 256, 0, stream>>>(Hbf, pWm1a, nullptr, nullptr,
      nullptr, nullptr, nullptr, nullptr, 0, P1, nullptr, N);
  // P2 = H @ Wm1b  (bf16 out)
  gemm_kernel<<<gblocks, 256, 0, stream>>>(Hbf, pWm1b, nullptr, nullptr,
      nullptr, nullptr, nullptr, nullptr, 0, nullptr, P2, N);

  phase2_kernel<<<(N + 3) / 4, 256, 0, stream>>>(P1, P2, off, elist, val, Wm1, bm1, Qbf, S, N);

  // Hagg = Q @ Wm2 + S*bm2  (bf16 out)
  gemm_kernel<<<gblocks, 256, 0, stream>>>(Qbf, pWm2, nullptr, nullptr,
      nullptr, S, bm2, nullptr, 0, nullptr, Haggbf, N);
  // T = relu(H@Wu1a + Hagg@Wu1b + bu1)  (bf16 out)
  gemm_kernel<<<gblocks, 256, 0, stream>>>(Hbf, pWu1a, Haggbf, pWu1b,
      bu1, nullptr, nullptr, nullptr, 1, nullptr, Tbf, N);
  // out = h + T@Wu2 + bu2  (f32 out)
  gemm_kernel<<<gblocks, 256, 0, stream>>>(Tbf, pWu2, nullptr, nullptr,
      bu2, nullptr, nullptr, h, 0, out, nullptr, N);
}

// Round 2
// 174.426 us; speedup vs baseline: 1.7444x; 1.7444x over previous
//
#include <hip/hip_runtime.h>
#include <hip/hip_bf16.h>
#include <math.h>

#define D 256
#define HID 16

typedef __attribute__((ext_vector_type(8))) short bf16x8;
typedef __attribute__((ext_vector_type(4))) float f32x4;

__device__ __forceinline__ ushort f2b(float x){
  uint u = __float_as_uint(x);
  u = u + 0x7FFFu + ((u >> 16) & 1u);   // round-to-nearest-even
  return (ushort)(u >> 16);
}
__device__ __forceinline__ float b2f(ushort u){ return __uint_as_float(((uint)u) << 16); }

// ---- prep: h->bf16 convert + pack 6 weight matrices + zero deg ----
// packed B layout (nt-major so a 64-col tile is one contiguous 32KB chunk):
// pb[((nt*8 + kt)*64 + lane)*8 + i] = W[kt*32 + (lane>>4)*8 + i][nt*16 + (lane&15)]
__global__ void prep_kernel(const float* h, ushort* Hbf, int NC,
                            const float* Wm1, const float* Wm2,
                            const float* Wu1, const float* Wu2,
                            ushort* pAll, int* deg, int N){
  int idx = blockIdx.x * blockDim.x + threadIdx.x;
  if (idx < NC){ Hbf[idx] = f2b(h[idx]); return; }
  int q = idx - NC;
  if (q < 6 * 65536){
    int mat = q >> 16, p = q & 65535;
    int i = p & 7, l = (p >> 3) & 63, kt = (p >> 9) & 7, nt = p >> 12;
    int k = kt * 32 + ((l >> 4) * 8) + i;
    int n = nt * 16 + (l & 15);
    const float* src;
    switch (mat){
      case 0: src = Wm1 + (size_t)k * 256 + n; break;            // Wm1a
      case 1: src = Wm1 + (size_t)(256 + k) * 256 + n; break;    // Wm1b
      case 2: src = Wm2 + (size_t)k * 256 + n; break;
      case 3: src = Wu1 + (size_t)k * 256 + n; break;            // Wu1a
      case 4: src = Wu1 + (size_t)(256 + k) * 256 + n; break;    // Wu1b
      default: src = Wu2 + (size_t)k * 256 + n; break;
    }
    pAll[q] = f2b(*src);
    return;
  }
  q -= 6 * 65536;
  if (q < N) deg[q] = 0;
}

// ---- edge bucketing (counting sort by row) ----
__global__ void count_kernel(const int* row, int* deg, int E){
  int e = blockIdx.x * blockDim.x + threadIdx.x;
  if (e < E) atomicAdd(&deg[row[e]], 1);
}

__global__ void scan_kernel(const int* deg, int* off, int* cur, int N){
  const int CH = 16; // 1024*16 = 16384 >= N
  int t = threadIdx.x;
  int vals[CH], loc[CH]; int s = 0;
  #pragma unroll
  for (int i = 0; i < CH; ++i){
    int idx = t * CH + i;
    int v = (idx < N) ? deg[idx] : 0;
    vals[i] = v; loc[i] = s; s += v;
  }
  __shared__ int sm[1024];
  sm[t] = s;
  __syncthreads();
  for (int d = 1; d < 1024; d <<= 1){
    int v = (t >= d) ? sm[t - d] : 0;
    __syncthreads();
    sm[t] += v;
    __syncthreads();
  }
  int excl = sm[t] - s;
  #pragma unroll
  for (int i = 0; i < CH; ++i){
    int idx = t * CH + i;
    if (idx < N){
      int o = excl + loc[i];
      off[idx] = o; cur[idx] = o;
      if (idx == N - 1) off[N] = o + vals[i];
    }
  }
}

// ---- fill: bucket edges, attention MLP computed inline ----
__global__ void fill_kernel(const int* ei, const int* val,
                            const float* Wa1, const float* ba1,
                            const float* Wa2, const float* ba2,
                            int* cur, uint2* elist, int E){
  int e = blockIdx.x * blockDim.x + threadIdx.x;
  if (e >= E) return;
  int r = ei[e], c = ei[E + e];
  int vri = val[r], vci = val[c];
  float vr = (float)vri, vc = (float)vci;
  float s = ba2[0];
  #pragma unroll
  for (int j = 0; j < HID; ++j){
    float hj = fmaxf(vr * Wa1[j] + vc * Wa1[HID + j] + ba1[j], 0.f);
    s += hj * Wa2[j];
  }
  float att = 1.f / (1.f + expf(-s));
  int pos = atomicAdd(&cur[r], 1);
  elist[pos] = make_uint2((uint)c | ((uint)vci << 16), __float_as_uint(att));
}

// ---- phase2: per-row edge aggregation.
// Q[r] = sum_e att * relu(P1[r] + P2[col] + vr*wvr + vc*wvc + bm1); S[r] = sum_e att
__global__ __launch_bounds__(256) void phase2_kernel(
    const float* P1, const ushort* P2, const int* off, const uint2* elist,
    const int* val, const float* Wm1, const float* bm1,
    ushort* Qbf, float* S, int N){
  int wave = threadIdx.x >> 6, lane = threadIdx.x & 63;
  int r = blockIdx.x * 4 + wave;
  if (r >= N) return;
  int f0 = lane * 4;
  const float* wvr = Wm1 + (size_t)512 * 256;
  const float* wvc = Wm1 + (size_t)513 * 256;
  float4 p1 = *(const float4*)(P1 + (size_t)r * D + f0);
  float4 wr = *(const float4*)(wvr + f0);
  float4 wv = *(const float4*)(wvc + f0);
  float4 bb = *(const float4*)(bm1 + f0);
  float vrf = (float)val[r];
  float bx = p1.x + vrf * wr.x + bb.x;
  float by = p1.y + vrf * wr.y + bb.y;
  float bz = p1.z + vrf * wr.z + bb.z;
  float bw = p1.w + vrf * wr.w + bb.w;
  float ax = 0.f, ay = 0.f, az = 0.f, aw = 0.f, satt = 0.f;
  int e0 = off[r], e1 = off[r + 1];
  int e = e0;
  for (; e + 2 <= e1; e += 2){
    uint2 pa = elist[e], pb = elist[e + 1];
    int ca = (int)(pa.x & 0xFFFFu), cb = (int)(pb.x & 0xFFFFu);
    float vca = (float)(pa.x >> 16), vcb = (float)(pb.x >> 16);
    float atta = __uint_as_float(pa.y), attb = __uint_as_float(pb.y);
    ushort4 va = *(const ushort4*)(P2 + (size_t)ca * D + f0);
    ushort4 vb = *(const ushort4*)(P2 + (size_t)cb * D + f0);
    float zx = bx + b2f(va.x) + vca * wv.x;
    float zy = by + b2f(va.y) + vca * wv.y;
    float zz = bz + b2f(va.z) + vca * wv.z;
    float zw = bw + b2f(va.w) + vca * wv.w;
    ax += atta * fmaxf(zx, 0.f);
    ay += atta * fmaxf(zy, 0.f);
    az += atta * fmaxf(zz, 0.f);
    aw += atta * fmaxf(zw, 0.f);
    zx = bx + b2f(vb.x) + vcb * wv.x;
    zy = by + b2f(vb.y) + vcb * wv.y;
    zz = bz + b2f(vb.z) + vcb * wv.z;
    zw = bw + b2f(vb.w) + vcb * wv.w;
    ax += attb * fmaxf(zx, 0.f);
    ay += attb * fmaxf(zy, 0.f);
    az += attb * fmaxf(zz, 0.f);
    aw += attb * fmaxf(zw, 0.f);
    satt += atta + attb;
  }
  if (e < e1){
    uint2 pa = elist[e];
    int ca = (int)(pa.x & 0xFFFFu);
    float vca = (float)(pa.x >> 16);
    float atta = __uint_as_float(pa.y);
    ushort4 va = *(const ushort4*)(P2 + (size_t)ca * D + f0);
    float zx = bx + b2f(va.x) + vca * wv.x;
    float zy = by + b2f(va.y) + vca * wv.y;
    float zz = bz + b2f(va.z) + vca * wv.z;
    float zw = bw + b2f(va.w) + vca * wv.w;
    ax += atta * fmaxf(zx, 0.f);
    ay += atta * fmaxf(zy, 0.f);
    az += atta * fmaxf(zz, 0.f);
    aw += atta * fmaxf(zw, 0.f);
    satt += atta;
  }
  ushort4 q; q.x = f2b(ax); q.y = f2b(ay); q.z = f2b(az); q.w = f2b(aw);
  *(ushort4*)(Qbf + (size_t)r * D + f0) = q;
  if (lane == 0) S[r] = satt;
}

// ---- fused GEMM v2: BM=128 x BN=64 tiles, B staged in LDS via global_load_lds.
// C = [relu]( A1@B1 (+ A2@B2) (+ bias) (+ rowscale*rsvec) ) (+ resid)
// split: cols<256 -> outF (f32), cols>=256 -> outB (bf16, col-256)
__global__ __launch_bounds__(256) void gemm_kernel(
    const ushort* __restrict__ A1, const ushort* __restrict__ B1,
    const ushort* __restrict__ A2, const ushort* __restrict__ B2,
    const float* __restrict__ bias, const float* __restrict__ rowscale,
    const float* __restrict__ rsvec, const float* __restrict__ resid,
    int do_relu, int split, int nblocks,
    float* outF, ushort* outB, int M){
  extern __shared__ ushort ldsB[];
  int tid = threadIdx.x;
  int bn = blockIdx.x % nblocks;
  int bm = blockIdx.x / nblocks;

  {
    const ushort* src = B1 + (size_t)bn * 16384 + tid * 8;
    ushort* dst = ldsB + tid * 8;
    #pragma unroll
    for (int c = 0; c < 8; ++c)
      __builtin_amdgcn_global_load_lds(
        (const __attribute__((address_space(1))) uint*)(src + c * 2048),
        (__attribute__((address_space(3))) uint*)(dst + c * 2048), 16, 0, 0);
  }
  if (A2){
    const ushort* src = B2 + (size_t)bn * 16384 + tid * 8;
    ushort* dst = ldsB + 16384 + tid * 8;
    #pragma unroll
    for (int c = 0; c < 8; ++c)
      __builtin_amdgcn_global_load_lds(
        (const __attribute__((address_space(1))) uint*)(src + c * 2048),
        (__attribute__((address_space(3))) uint*)(dst + c * 2048), 16, 0, 0);
  }
  __syncthreads();

  int wave = tid >> 6, lane = tid & 63;
  int rbase = bm * 128 + wave * 32;
  int r0 = min(rbase + (lane & 15), M - 1);
  int r1 = min(rbase + 16 + (lane & 15), M - 1);
  int kl = (lane >> 4) * 8;

  f32x4 zero = {0.f, 0.f, 0.f, 0.f};
  f32x4 acc[2][4];
  #pragma unroll
  for (int a = 0; a < 2; ++a)
    #pragma unroll
    for (int b = 0; b < 4; ++b) acc[a][b] = zero;

  {
    const ushort* ap0 = A1 + (size_t)r0 * 256 + kl;
    const ushort* ap1 = A1 + (size_t)r1 * 256 + kl;
    #pragma unroll
    for (int kt = 0; kt < 8; ++kt){
      bf16x8 b0 = *(const bf16x8*)(ldsB + ((size_t)(0 * 8 + kt) * 64 + lane) * 8);
      bf16x8 b1 = *(const bf16x8*)(ldsB + ((size_t)(1 * 8 + kt) * 64 + lane) * 8);
      bf16x8 b2 = *(const bf16x8*)(ldsB + ((size_t)(2 * 8 + kt) * 64 + lane) * 8);
      bf16x8 b3 = *(const bf16x8*)(ldsB + ((size_t)(3 * 8 + kt) * 64 + lane) * 8);
      bf16x8 a0 = *(const bf16x8*)(ap0 + kt * 32);
      bf16x8 a1 = *(const bf16x8*)(ap1 + kt * 32);
      acc[0][0] = __builtin_amdgcn_mfma_f32_16x16x32_bf16(a0, b0, acc[0][0], 0, 0, 0);
      acc[0][1] = __builtin_amdgcn_mfma_f32_16x16x32_bf16(a0, b1, acc[0][1], 0, 0, 0);
      acc[0][2] = __builtin_amdgcn_mfma_f32_16x16x32_bf16(a0, b2, acc[0][2], 0, 0, 0);
      acc[0][3] = __builtin_amdgcn_mfma_f32_16x16x32_bf16(a0, b3, acc[0][3], 0, 0, 0);
      acc[1][0] = __builtin_amdgcn_mfma_f32_16x16x32_bf16(a1, b0, acc[1][0], 0, 0, 0);
      acc[1][1] = __builtin_amdgcn_mfma_f32_16x16x32_bf16(a1, b1, acc[1][1], 0, 0, 0);
      acc[1][2] = __builtin_amdgcn_mfma_f32_16x16x32_bf16(a1, b2, acc[1][2], 0, 0, 0);
      acc[1][3] = __builtin_amdgcn_mfma_f32_16x16x32_bf16(a1, b3, acc[1][3], 0, 0, 0);
    }
  }
  if (A2){
    const ushort* ap0 = A2 + (size_t)r0 * 256 + kl;
    const ushort* ap1 = A2 + (size_t)r1 * 256 + kl;
    #pragma unroll
    for (int kt = 0; kt < 8; ++kt){
      bf16x8 b0 = *(const bf16x8*)(ldsB + 16384 + ((size_t)(0 * 8 + kt) * 64 + lane) * 8);
      bf16x8 b1 = *(const bf16x8*)(ldsB + 16384 + ((size_t)(1 * 8 + kt) * 64 + lane) * 8);
      bf16x8 b2 = *(const bf16x8*)(ldsB + 16384 + ((size_t)(2 * 8 + kt) * 64 + lane) * 8);
      bf16x8 b3 = *(const bf16x8*)(ldsB + 16384 + ((size_t)(3 * 8 + kt) * 64 + lane) * 8);
      bf16x8 a0 = *(const bf16x8*)(ap0 + kt * 32);
      bf16x8 a1 = *(const bf16x8*)(ap1 + kt * 32);
      acc[0][0] = __builtin_amdgcn_mfma_f32_16x16x32_bf16(a0, b0, acc[0][0], 0, 0, 0);
      acc[0][1] = __builtin_amdgcn_mfma_f32_16x16x32_bf16(a0, b1, acc[0][1], 0, 0, 0);
      acc[0][2] = __builtin_amdgcn_mfma_f32_16x16x32_bf16(a0, b2, acc[0][2], 0, 0, 0);
      acc[0][3] = __builtin_amdgcn_mfma_f32_16x16x32_bf16(a0, b3, acc[0][3], 0, 0, 0);
      acc[1][0] = __builtin_amdgcn_mfma_f32_16x16x32_bf16(a1, b0, acc[1][0], 0, 0, 0);
      acc[1][1] = __builtin_amdgcn_mfma_f32_16x16x32_bf16(a1, b1, acc[1][1], 0, 0, 0);
      acc[1][2] = __builtin_amdgcn_mfma_f32_16x16x32_bf16(a1, b2, acc[1][2], 0, 0, 0);
      acc[1][3] = __builtin_amdgcn_mfma_f32_16x16x32_bf16(a1, b3, acc[1][3], 0, 0, 0);
    }
  }

  int coll = lane & 15, rl = (lane >> 4) * 4;
  #pragma unroll
  for (int rt = 0; rt < 2; ++rt){
    #pragma unroll
    for (int n = 0; n < 4; ++n){
      int cg = bn * 64 + n * 16 + coll;
      float bc = bias ? bias[cg] : 0.f;
      float vcv = rowscale ? rsvec[cg] : 0.f;
      #pragma unroll
      for (int j = 0; j < 4; ++j){
        int r = rbase + rt * 16 + rl + j;
        if (r < M){
          float v = acc[rt][n][j] + bc;
          if (rowscale) v += rowscale[r] * vcv;
          if (do_relu) v = fmaxf(v, 0.f);
          if (resid) v += resid[(size_t)r * 256 + cg];
          if (split){
            if (cg < 256) outF[(size_t)r * 256 + cg] = v;
            else outB[(size_t)r * 256 + (cg - 256)] = f2b(v);
          } else {
            if (outF) outF[(size_t)r * 256 + cg] = v;
            if (outB) outB[(size_t)r * 256 + cg] = f2b(v);
          }
        }
      }
    }
  }
}

extern "C" void kernel_launch(void* const* d_in, const int* in_sizes, int n_in,
                              void* d_out, int out_size, void* d_ws, size_t ws_size,
                              hipStream_t stream){
  const float* h   = (const float*)d_in[0];
  const int*   ei  = (const int*)d_in[1];
  const int*   val = (const int*)d_in[3];
  const float* Wm1 = (const float*)d_in[4];
  const float* bm1 = (const float*)d_in[5];
  const float* Wm2 = (const float*)d_in[6];
  const float* bm2 = (const float*)d_in[7];
  const float* Wu1 = (const float*)d_in[8];
  const float* bu1 = (const float*)d_in[9];
  const float* Wu2 = (const float*)d_in[10];
  const float* bu2 = (const float*)d_in[11];
  const float* Wa1 = (const float*)d_in[12];
  const float* ba1 = (const float*)d_in[13];
  const float* Wa2 = (const float*)d_in[14];
  const float* ba2 = (const float*)d_in[15];
  int N = in_sizes[0] / D;
  int E = in_sizes[1] / 2;
  float* out = (float*)d_out;

  char* ws = (char*)d_ws;
  size_t o = 0;
  auto alloc = [&](size_t bytes)->char*{
    char* p = ws + o; o += (bytes + 255) & ~(size_t)255; return p;
  };
  float*  P1     = (float*) alloc((size_t)N * D * 4);
  ushort* P2     = (ushort*)alloc((size_t)N * D * 2);
  ushort* Hbf    = (ushort*)alloc((size_t)N * D * 2);
  ushort* Qbf    = (ushort*)alloc((size_t)N * D * 2);
  ushort* Haggbf = (ushort*)alloc((size_t)N * D * 2);
  ushort* Tbf    = (ushort*)alloc((size_t)N * D * 2);
  float*  S      = (float*) alloc((size_t)N * 4);
  int*    deg    = (int*)   alloc((size_t)N * 4);
  int*    off    = (int*)   alloc(((size_t)N + 1) * 4);
  int*    cur    = (int*)   alloc((size_t)N * 4);
  uint2*  elist  = (uint2*) alloc((size_t)E * 8);
  ushort* pAll   = (ushort*)alloc((size_t)6 * 65536 * 2);
  ushort* pWm1c  = pAll;               // [Wm1a|Wm1b] = 2*65536 (N=512 cat)
  ushort* pWm2   = pAll + 2 * 65536;
  ushort* pWu1a  = pAll + 3 * 65536;
  ushort* pWu1b  = pAll + 4 * 65536;
  ushort* pWu2   = pAll + 5 * 65536;

  int NC = N * D;
  int prep_total = NC + 6 * 65536 + N;
  prep_kernel<<<(prep_total + 255) / 256, 256, 0, stream>>>(
      h, Hbf, NC, Wm1, Wm2, Wu1, Wu2, pAll, deg, N);

  count_kernel<<<(E + 255) / 256, 256, 0, stream>>>(ei, deg, E);
  scan_kernel<<<1, 1024, 0, stream>>>(deg, off, cur, N);
  fill_kernel<<<(E + 255) / 256, 256, 0, stream>>>(ei, val, Wa1, ba1, Wa2, ba2, cur, elist, E);

  int mblocks = (N + 127) / 128;
  // G1: [P1|P2] = H @ [Wm1a|Wm1b]   (split output: f32 | bf16)
  gemm_kernel<<<mblocks * 8, 256, 32768, stream>>>(
      Hbf, pWm1c, nullptr, nullptr,
      nullptr, nullptr, nullptr, nullptr, 0, 1, 8, P1, P2, N);

  phase2_kernel<<<(N + 3) / 4, 256, 0, stream>>>(P1, P2, off, elist, val, Wm1, bm1, Qbf, S, N);

  // G2: Hagg = Q @ Wm2 + S*bm2  (bf16 out)
  gemm_kernel<<<mblocks * 4, 256, 32768, stream>>>(
      Qbf, pWm2, nullptr, nullptr,
      nullptr, S, bm2, nullptr, 0, 0, 4, nullptr, Haggbf, N);
  // G3: T = relu(H@Wu1a + Hagg@Wu1b + bu1)  (bf16 out)
  gemm_kernel<<<mblocks * 4, 256, 65536, stream>>>(
      Hbf, pWu1a, Haggbf, pWu1b,
      bu1, nullptr, nullptr, nullptr, 1, 0, 4, nullptr, Tbf, N);
  // G4: out = h + T@Wu2 + bu2  (f32 out)
  gemm_kernel<<<mblocks * 4, 256, 32768, stream>>>(
      Tbf, pWu2, nullptr, nullptr,
      bu2, nullptr, nullptr, h, 0, 0, 4, out, nullptr, N);
}